// Round 8
// baseline (1225.217 us; speedup 1.0000x reference)
//
#include <hip/hip_runtime.h>

#define DM     512
#define LAT    128
#define WIN_   256
#define ENC    55
#define GB     32        // batch groups
#define BT     8         // batch rows per group
#define DS     64        // h-dims per slice
#define TPB    768       // 12 waves
#define OUT_T  256
#define AROW16 528       // u16 per smemA row (512 data + 16 pad)
#define GHS    200       // ghT row stride in floats
#define OWS    520       // sOutW row stride in u16
#define NK     22        // records per (row, slice): ceil(64/3)
#define NKP    24        // padded record slots

typedef __attribute__((ext_vector_type(8))) short bf8;
typedef __attribute__((ext_vector_type(4))) float f4;
typedef unsigned long long u64;
typedef unsigned short u16;

// .bss scratch: zero at load, not poisoned by the harness.
// Record u64 = [seq16 | bf16 d0 | bf16 d1 | bf16 d2] — single-copy atomic, so
// seq and data are always consistent: no flags, no producer drain, 1-RT consume.
__device__ __align__(128) u64 g_ring2[2][GB][8][BT][NKP];  // 786 KB
__device__ __align__(128) u64 g_lcnt[GB * 8 * 16];         // per-(g,s) launch count

__device__ __forceinline__ u16 f2bf(float f) {
    union { float f; unsigned int i; } v; v.f = f;
    unsigned int r = v.i + 0x7fffu + ((v.i >> 16) & 1u);
    return (u16)(r >> 16);
}
__device__ __forceinline__ float sigm(float x) { return 1.f / (1.f + __expf(-x)); }
__device__ __forceinline__ float tanh_(float x) {
    x = fminf(x, 40.f);
    float e = __expf(2.f * x);
    return (e - 1.f) / (e + 1.f);
}
#define ALOAD(p)     __hip_atomic_load((p),      __ATOMIC_RELAXED, __HIP_MEMORY_SCOPE_AGENT)
#define ASTORE(p, v) __hip_atomic_store((p), (v), __ATOMIC_RELAXED, __HIP_MEMORY_SCOPE_AGENT)

// Persistent fused GRU+projection, self-validating record dataflow.
// 256 blocks = 32 batch-groups x 8 d-slices. Per step:
//   wave 0     : gate math (9 dims/lane in regs) -> pack records -> fire-and-forget
//   waves 1-7  : spin-load ONE remote slice's 22x8 records until seq==want
//                (data arrives with the detecting load), unpack into LDS
//   all 12     : gate GEMM (16 MFMA) vs resident w_hh fragments
//   waves 8-11 : projection vs LDS-resident bf16 out_w (1-in-8 steps per block)
// Launch-base: per-(g,s) counter only its own block touches; +1 per launch at
// exit; base_seq = count*512 (stride > in-launch range 257 -> no stale aliasing).
__global__ __launch_bounds__(TPB, 3) void gru_fused(
    const float* __restrict__ z,    // [256][128]
    const float* __restrict__ hpw,  // [512][128]
    const float* __restrict__ hpb,  // [512]
    const float* __restrict__ whh,  // [1536][512]
    const float* __restrict__ bih,  // [1536]
    const float* __restrict__ bhh,  // [1536]
    const float* __restrict__ outw, // [55][512]
    const float* __restrict__ outb, // [55]
    float* __restrict__ out)        // [256][256][55] fp32
{
    const int blk  = blockIdx.x;
    const int g    = blk & (GB - 1);
    const int s    = blk >> 5;
    const int d0   = s * DS;
    const int row0 = g * BT;
    const int tid  = threadIdx.x;
    const int wave = tid >> 6;
    const int lane = tid & 63;
    const int quad = lane >> 4;
    const int nl   = lane & 15;

    __shared__ __align__(16) u16 sm16[BT * AROW16];   // staged h(t-1) bf16
    __shared__ __align__(16) float ghT[BT][GHS];      // [batch][gate*64+dim]
    __shared__ float bias_r[DS], bias_z[DS], gin_[DS], bhn_[DS];
    __shared__ __align__(16) float h0tmp[BT][DS];
    __shared__ __align__(16) u16 sOutW[ENC * OWS];    // bf16 out_w, padded
    __shared__ float sOutB[64];
    __shared__ u64 sh_base;

    u64* lc_own = g_lcnt + (u64)(g * 8 + s) * 16;
    if (tid == 0) sh_base = ALOAD(lc_own) * 512ULL;

    if (tid < DS) {
        int dg = d0 + tid;
        bias_r[tid] = bih[dg]       + bhh[dg];
        bias_z[tid] = bih[512 + dg] + bhh[512 + dg];
        gin_[tid]   = bih[1024 + dg];
        bhn_[tid]   = bhh[1024 + dg];
    }
    if (tid < ENC) sOutB[tid] = outb[tid];
    for (int i = tid; i < ENC * DM; i += TPB)
        sOutW[(i >> 9) * OWS + (i & 511)] = f2bf(outw[i]);

    // Resident w_hh B-fragments: this wave's 16 gate rows x K=512.
    const int gl   = wave * 16 + nl;
    const int sel  = gl >> 6;
    const int jrow = sel * 512 + d0 + (gl & 63);
    bf8 bfrag[16];
#pragma unroll
    for (int kb = 0; kb < 16; ++kb) {
        const float* wp = whh + jrow * DM + kb * 32 + quad * 8;
        bf8 v;
#pragma unroll
        for (int j = 0; j < 8; ++j) v[j] = (short)f2bf(wp[j]);
        bfrag[kb] = v;
    }

    // h0 = tanh(z @ hpw^T + hpb)
    if (tid < BT * DS) {
        int d = tid & (DS - 1), bl = tid >> 6;
        float acc = hpb[d0 + d];
        const float* zr = z + (row0 + bl) * LAT;
        const float* wr = hpw + (d0 + d) * LAT;
#pragma unroll 8
        for (int k = 0; k < LAT; ++k) acc += zr[k] * wr[k];
        h0tmp[bl][d] = tanh_(acc);
    }
    __syncthreads();

    const u64 base = sh_base;
    const int prow = lane >> 3;       // wave-0 row
    const int kc   = lane & 7;        // record column base

    // wave-0 register state: h for records k = kc, kc+8, kc+16 (3 dims each)
    float hreg[3][3];
    if (wave == 0) {
#pragma unroll
        for (int m = 0; m < 3; ++m) {
            int k = kc + 8 * m;
#pragma unroll
            for (int i = 0; i < 3; ++i) {
                int d = 3 * k + i;
                hreg[m][i] = (k < NK && d < DS) ? h0tmp[prow][d] : 0.f;
            }
        }
        // publish h(0): records seq = base+0, slot 0 (fire-and-forget)
        const u16 sq = (u16)base;
#pragma unroll
        for (int m = 0; m < 3; ++m) {
            int k = kc + 8 * m;
            if (k < NK) {
                u64 rec = (u64)sq | ((u64)f2bf(hreg[m][0]) << 16) |
                          ((u64)f2bf(hreg[m][1]) << 32) | ((u64)f2bf(hreg[m][2]) << 48);
                ASTORE(&g_ring2[0][g][s][prow][k], rec);
            }
        }
    }

    const u16* afrag_base = sm16 + (nl & 7) * AROW16;

    for (int t = 1; t <= WIN_; ++t) {
        const int sp = (t - 1) & 1, sc = t & 1;
        const u16 want = (u16)(base + t - 1);

        // ---- stage h(t-1) into sm16 ----
        if (wave == 0) {
#pragma unroll
            for (int m = 0; m < 3; ++m) {
                int k = kc + 8 * m;
#pragma unroll
                for (int i = 0; i < 3; ++i) {
                    int d = 3 * k + i;
                    if (k < NK && d < DS) sm16[prow * AROW16 + d0 + d] = f2bf(hreg[m][i]);
                }
            }
        } else if (wave < 8) {
            const int j = (s + wave) & 7;
            u64* p0 = &g_ring2[sp][g][j][prow][kc];
            u64 r0, r1, r2;
            long guard = 0;
            const bool v2 = (kc + 16) < NK;
            for (;;) {
                r0 = ALOAD(p0);
                r1 = ALOAD(p0 + 8);
                r2 = v2 ? ALOAD(p0 + 16) : 0;
                bool ok = ((u16)r0 == want) && ((u16)r1 == want) &&
                          (!v2 || (u16)r2 == want);
                if (__all(ok) || ++guard > (1L << 20)) break;
            }
            u16* dst = sm16 + prow * AROW16 + j * 64;
            {
                int db = 3 * kc;
                dst[db] = (u16)(r0 >> 16); dst[db + 1] = (u16)(r0 >> 32); dst[db + 2] = (u16)(r0 >> 48);
                db = 3 * (kc + 8);
                dst[db] = (u16)(r1 >> 16); dst[db + 1] = (u16)(r1 >> 32); dst[db + 2] = (u16)(r1 >> 48);
                if (v2) {
                    db = 3 * (kc + 16);
                    dst[db] = (u16)(r2 >> 16);
                    if (db + 1 < DS) dst[db + 1] = (u16)(r2 >> 32);
                    if (db + 2 < DS) dst[db + 2] = (u16)(r2 >> 48);
                }
            }
        }
        __syncthreads();  // A: tile complete

        // ---- gate GEMM: 192 rows x K=512 ----
        f4 acc = {0.f, 0.f, 0.f, 0.f};
#pragma unroll
        for (int kb = 0; kb < 16; ++kb) {
            bf8 av = *(const bf8*)(afrag_base + quad * 8 + kb * 32);
            acc = __builtin_amdgcn_mfma_f32_16x16x32_bf16(av, bfrag[kb], acc, 0, 0, 0);
        }
        if (quad < 2) {
            const int c = sel * 64 + (gl & 63);
#pragma unroll
            for (int r = 0; r < 4; ++r) ghT[quad * 4 + r][c] = acc[r];
        }
        __syncthreads();  // B: ghT complete

        // ---- wave 0: gate update + publish (group-critical path) ----
        if (wave == 0) {
            const float* grow = &ghT[prow][0];
            const u16 sq = (u16)(base + t);
#pragma unroll
            for (int m = 0; m < 3; ++m) {
                int k = kc + 8 * m;
                if (k < NK) {
                    u16 b[3] = {0, 0, 0};
#pragma unroll
                    for (int i = 0; i < 3; ++i) {
                        int d = 3 * k + i;
                        if (d < DS) {
                            float rr = sigm(bias_r[d] + grow[d]);
                            float zg = sigm(bias_z[d] + grow[64 + d]);
                            float nn = tanh_(gin_[d] + rr * (bhn_[d] + grow[128 + d]));
                            float h  = (1.f - zg) * nn + zg * hreg[m][i];
                            hreg[m][i] = h;
                            b[i] = f2bf(h);
                        }
                    }
                    u64 rec = (u64)sq | ((u64)b[0] << 16) | ((u64)b[1] << 32) | ((u64)b[2] << 48);
                    ASTORE(&g_ring2[sc][g][s][prow][k], rec);
                }
            }
        }

        // ---- waves 8-11: projection out[:,tau,:] from sm16 (h(tau+1)=h(t-1)) ----
        const int tau = t - 2;
        const bool proj = (tau >= 0) && ((tau & 7) == s);
        if (proj && wave >= 8) {
            const int e  = (wave - 8) * 16 + nl;
            const int ec = (e < ENC) ? e : (ENC - 1);
            const u16* wrow = sOutW + ec * OWS + quad * 8;
            f4 accp = {0.f, 0.f, 0.f, 0.f};
#pragma unroll
            for (int kb = 0; kb < 16; ++kb) {
                bf8 av = *(const bf8*)(afrag_base + quad * 8 + kb * 32);
                bf8 wv = *(const bf8*)(wrow + kb * 32);
                accp = __builtin_amdgcn_mfma_f32_16x16x32_bf16(av, wv, accp, 0, 0, 0);
            }
            if (quad < 2 && e < ENC) {
                float ob = sOutB[e];
#pragma unroll
                for (int r = 0; r < 4; ++r) {
                    int m = quad * 4 + r;
                    out[(row0 + m) * (OUT_T * ENC) + tau * ENC + e] = accp[r] + ob;
                }
            }
        }
        if (proj) __syncthreads();  // C: protect sm16 from next-step writes
    }

    // ---- tail: tau=255 uses h(256) (slot 0, seq base+256), s==7 only ----
    if (s == 7) {
        const u16 want = (u16)(base + WIN_);
        if (wave == 0) {
#pragma unroll
            for (int m = 0; m < 3; ++m) {
                int k = kc + 8 * m;
#pragma unroll
                for (int i = 0; i < 3; ++i) {
                    int d = 3 * k + i;
                    if (k < NK && d < DS) sm16[prow * AROW16 + d0 + d] = f2bf(hreg[m][i]);
                }
            }
        } else if (wave < 8) {
            const int j = (s + wave) & 7;
            u64* p0 = &g_ring2[0][g][j][prow][kc];
            u64 r0, r1, r2;
            long guard = 0;
            const bool v2 = (kc + 16) < NK;
            for (;;) {
                r0 = ALOAD(p0);
                r1 = ALOAD(p0 + 8);
                r2 = v2 ? ALOAD(p0 + 16) : 0;
                bool ok = ((u16)r0 == want) && ((u16)r1 == want) &&
                          (!v2 || (u16)r2 == want);
                if (__all(ok) || ++guard > (1L << 20)) break;
            }
            u16* dst = sm16 + prow * AROW16 + j * 64;
            int db = 3 * kc;
            dst[db] = (u16)(r0 >> 16); dst[db + 1] = (u16)(r0 >> 32); dst[db + 2] = (u16)(r0 >> 48);
            db = 3 * (kc + 8);
            dst[db] = (u16)(r1 >> 16); dst[db + 1] = (u16)(r1 >> 32); dst[db + 2] = (u16)(r1 >> 48);
            if (v2) {
                db = 3 * (kc + 16);
                dst[db] = (u16)(r2 >> 16);
                if (db + 1 < DS) dst[db + 1] = (u16)(r2 >> 32);
                if (db + 2 < DS) dst[db + 2] = (u16)(r2 >> 48);
            }
        }
        __syncthreads();
        if (wave >= 8) {
            const int e  = (wave - 8) * 16 + nl;
            const int ec = (e < ENC) ? e : (ENC - 1);
            const u16* wrow = sOutW + ec * OWS + quad * 8;
            f4 accp = {0.f, 0.f, 0.f, 0.f};
#pragma unroll
            for (int kb = 0; kb < 16; ++kb) {
                bf8 av = *(const bf8*)(afrag_base + quad * 8 + kb * 32);
                bf8 wv = *(const bf8*)(wrow + kb * 32);
                accp = __builtin_amdgcn_mfma_f32_16x16x32_bf16(av, wv, accp, 0, 0, 0);
            }
            if (quad < 2 && e < ENC) {
                float ob = sOutB[e];
#pragma unroll
                for (int r = 0; r < 4; ++r) {
                    int m = quad * 4 + r;
                    out[(row0 + m) * (OUT_T * ENC) + 255 * ENC + e] = accp[r] + ob;
                }
            }
        }
    }

    // bump own launch counter (next launch's base); kernel boundary publishes it
    __syncthreads();
    if (tid == 0) ASTORE(lc_own, (base / 512ULL) + 1ULL);
}

extern "C" void kernel_launch(void* const* d_in, const int* in_sizes, int n_in,
                              void* d_out, int out_size, void* d_ws, size_t ws_size,
                              hipStream_t stream) {
    const float* z    = (const float*)d_in[0];
    const float* hpw  = (const float*)d_in[1];
    const float* hpb  = (const float*)d_in[2];
    // d_in[3] = w_ih: unused by the reference (input gates are pure biases)
    const float* whh  = (const float*)d_in[4];
    const float* bih  = (const float*)d_in[5];
    const float* bhh  = (const float*)d_in[6];
    const float* outw = (const float*)d_in[7];
    const float* outb = (const float*)d_in[8];
    float* out = (float*)d_out;

    (void)d_ws; (void)ws_size;  // scratch lives in module .bss
    gru_fused<<<dim3(256), dim3(TPB), 0, stream>>>(
        z, hpw, hpb, whh, bih, bhh, outw, outb, out);
}

// Round 9
// 698.507 us; speedup vs baseline: 1.7541x; 1.7541x over previous
//
#include <hip/hip_runtime.h>

#define DM     512
#define LAT    128
#define WIN_   256
#define ENC    55
#define GB     32        // batch groups
#define BT     8         // batch rows per group
#define DS     64        // h-dims per slice
#define TPB    768       // 12 waves
#define OUT_T  256
#define AROW16 528       // u16 per sm16 row (512 data + 16 pad)
#define GHS    200       // ghT row stride in floats
#define OWS    520       // sOutW row stride in u16
#define NK     22        // records per (row, slice): ceil(64/3)
#define NKP    24        // padded record slots

typedef __attribute__((ext_vector_type(8))) short bf8;
typedef __attribute__((ext_vector_type(4))) float f4;
typedef unsigned long long u64;
typedef unsigned short u16;

// .bss scratch: zero at load, not poisoned by the harness.
// Record u64 = [seq16 | bf16 d0 | bf16 d1 | bf16 d2] — single-copy atomic:
// seq and data always consistent. Producers fire-and-forget (no drain, no flag).
// Consumers poll ONE broadcast address, then fetch-once + validate + retry
// stragglers (R8 regression was full-payload polling flooding the MALL).
__device__ __align__(128) u64 g_ring2[2][GB][8][BT][NKP];  // ~786 KB
__device__ __align__(128) u64 g_lcnt[GB * 8 * 16];         // per-(g,s) launch count

__device__ __forceinline__ u16 f2bf(float f) {
    union { float f; unsigned int i; } v; v.f = f;
    unsigned int r = v.i + 0x7fffu + ((v.i >> 16) & 1u);
    return (u16)(r >> 16);
}
__device__ __forceinline__ float sigm(float x) { return 1.f / (1.f + __expf(-x)); }
__device__ __forceinline__ float tanh_(float x) {
    x = fminf(x, 40.f);
    float e = __expf(2.f * x);
    return (e - 1.f) / (e + 1.f);
}
#define ALOAD(p)     __hip_atomic_load((p),      __ATOMIC_RELAXED, __HIP_MEMORY_SCOPE_AGENT)
#define ASTORE(p, v) __hip_atomic_store((p), (v), __ATOMIC_RELAXED, __HIP_MEMORY_SCOPE_AGENT)

// Persistent fused GRU+projection. 256 blocks = 32 batch-groups x 8 d-slices.
// Per step: waves 0-7 stage own slice + poll/fetch/validate one remote slice;
// all 12 waves gate GEMM vs resident w_hh fragments; waves 0-7 gate math
// (1 dim/lane) -> pack records via LDS -> fire-and-forget publish;
// waves 8-11 projection vs LDS-resident bf16 out_w (1-in-8 steps per block).
// base = lc*512 + 1 (never 0 -> virgin .bss records can't validate; slot seq
// aliasing impossible: same-slot rewrite distance 2, launch stride 512).
__global__ __launch_bounds__(TPB, 3) void gru_fused(
    const float* __restrict__ z,    // [256][128]
    const float* __restrict__ hpw,  // [512][128]
    const float* __restrict__ hpb,  // [512]
    const float* __restrict__ whh,  // [1536][512]
    const float* __restrict__ bih,  // [1536]
    const float* __restrict__ bhh,  // [1536]
    const float* __restrict__ outw, // [55][512]
    const float* __restrict__ outb, // [55]
    float* __restrict__ out)        // [256][256][55] fp32
{
    const int blk  = blockIdx.x;
    const int g    = blk & (GB - 1);
    const int s    = blk >> 5;
    const int d0   = s * DS;
    const int row0 = g * BT;
    const int tid  = threadIdx.x;
    const int wave = tid >> 6;
    const int lane = tid & 63;
    const int quad = lane >> 4;
    const int nl   = lane & 15;

    __shared__ __align__(16) u16 sm16[BT * AROW16];   // staged h(t-1) bf16
    __shared__ __align__(16) float ghT[BT][GHS];      // [batch][gate*64+dim]
    __shared__ float bias_r[DS], bias_z[DS], gin_[DS], bhn_[DS];
    __shared__ __align__(16) u16 hpack[BT][66];       // bf16 h(t) rows + pad
    __shared__ __align__(16) u16 sOutW[ENC * OWS];    // bf16 out_w, padded
    __shared__ float sOutB[64];
    __shared__ u64 sh_lc;

    u64* lc_own = g_lcnt + (u64)(g * 8 + s) * 16;
    if (tid == 0) sh_lc = ALOAD(lc_own);

    if (tid < DS) {
        int dg = d0 + tid;
        bias_r[tid] = bih[dg]       + bhh[dg];
        bias_z[tid] = bih[512 + dg] + bhh[512 + dg];
        gin_[tid]   = bih[1024 + dg];
        bhn_[tid]   = bhh[1024 + dg];
    }
    if (tid < ENC) sOutB[tid] = outb[tid];
    for (int i = tid; i < ENC * DM; i += TPB)
        sOutW[(i >> 9) * OWS + (i & 511)] = f2bf(outw[i]);

    // Resident w_hh B-fragments: this wave's 16 gate rows x K=512.
    const int gl   = wave * 16 + nl;
    const int sel  = gl >> 6;
    const int jrow = sel * 512 + d0 + (gl & 63);
    bf8 bfrag[16];
#pragma unroll
    for (int kb = 0; kb < 16; ++kb) {
        const float* wp = whh + jrow * DM + kb * 32 + quad * 8;
        bf8 v;
#pragma unroll
        for (int j = 0; j < 8; ++j) v[j] = (short)f2bf(wp[j]);
        bfrag[kb] = v;
    }
    __syncthreads();  // sh_lc, biases, sOutW ready

    const u64 base = sh_lc * 512ULL + 1ULL;   // seq never 0 (virgin .bss)
    float hprev_reg = 0.f;                    // waves 0-7: h[row=wave][dim=lane]

    // h0 = tanh(z @ hpw^T + hpb): wave w lane d computes its own element
    if (wave < BT) {
        float acc = hpb[d0 + lane];
        const float* zr = z + (row0 + wave) * LAT;
        const float* wr = hpw + (d0 + lane) * LAT;
#pragma unroll 8
        for (int k = 0; k < LAT; ++k) acc += zr[k] * wr[k];
        hprev_reg = tanh_(acc);
        if (lane < 2) hpack[wave][64 + lane] = 0;   // zero record pads once
        hpack[wave][lane] = f2bf(hprev_reg);
        // publish h(0): seq = base, slot 0 (fire-and-forget)
        const u16 sq = (u16)base;
        if (lane < NK) {
            u16 b0 = hpack[wave][3 * lane], b1 = hpack[wave][3 * lane + 1],
                b2 = hpack[wave][3 * lane + 2];
            u64 rec = (u64)sq | ((u64)b0 << 16) | ((u64)b1 << 32) | ((u64)b2 << 48);
            ASTORE(&g_ring2[0][g][s][wave][lane], rec);
        }
    }

    const u16* afrag_base = sm16 + (nl & 7) * AROW16;

    for (int t = 1; t <= WIN_; ++t) {
        const int sp = (t - 1) & 1, sc = t & 1;
        const u16 want = (u16)(base + t - 1);

        // ---- stage h(t-1) into sm16 ----
        if (wave < BT) {
            sm16[wave * AROW16 + d0 + lane] = f2bf(hprev_reg);  // own slice
        }
        if (wave >= 1 && wave < 8) {
            const int j = (s + wave) & 7;
            const u64* rb = &g_ring2[sp][g][j][0][0];
            const int row = lane >> 3, k = lane & 7;
            // cheap poll: one broadcast address (late-issued record)
            {
                const u64* pp = rb + 7 * NKP + 21;
                long guard = 0;
                while ((u16)ALOAD(pp) != want && guard < (1L << 18)) ++guard;
            }
            // fetch once + validate + retry stragglers
            const u64* p0 = rb + row * NKP + k;
            const bool v2 = (k + 16) < NK;
            u64 r0 = ALOAD(p0), r1 = ALOAD(p0 + 8), r2 = v2 ? ALOAD(p0 + 16) : 0;
            bool ok0 = ((u16)r0 == want), ok1 = ((u16)r1 == want),
                 ok2 = (!v2) || ((u16)r2 == want);
            long guard = 0;
            while (!__all(ok0 && ok1 && ok2) && guard < (1L << 18)) {
                if (!ok0) { r0 = ALOAD(p0);      ok0 = ((u16)r0 == want); }
                if (!ok1) { r1 = ALOAD(p0 + 8);  ok1 = ((u16)r1 == want); }
                if (!ok2) { r2 = ALOAD(p0 + 16); ok2 = ((u16)r2 == want); }
                ++guard;
            }
            u16* dst = sm16 + row * AROW16 + j * 64;
            int db = 3 * k;
            dst[db] = (u16)(r0 >> 16); dst[db + 1] = (u16)(r0 >> 32); dst[db + 2] = (u16)(r0 >> 48);
            db = 3 * (k + 8);
            dst[db] = (u16)(r1 >> 16); dst[db + 1] = (u16)(r1 >> 32); dst[db + 2] = (u16)(r1 >> 48);
            if (v2) {
                db = 3 * (k + 16);
                dst[db] = (u16)(r2 >> 16);
                if (db + 1 < DS) dst[db + 1] = (u16)(r2 >> 32);
                if (db + 2 < DS) dst[db + 2] = (u16)(r2 >> 48);
            }
        }
        __syncthreads();  // A: tile complete

        // ---- gate GEMM: 192 rows x K=512 ----
        f4 acc = {0.f, 0.f, 0.f, 0.f};
#pragma unroll
        for (int kb = 0; kb < 16; ++kb) {
            bf8 av = *(const bf8*)(afrag_base + quad * 8 + kb * 32);
            acc = __builtin_amdgcn_mfma_f32_16x16x32_bf16(av, bfrag[kb], acc, 0, 0, 0);
        }
        if (quad < 2) {
#pragma unroll
            for (int r = 0; r < 4; ++r) ghT[quad * 4 + r][gl] = acc[r];
        }
        __syncthreads();  // B: ghT complete

        // ---- waves 0-7: gate update (1 dim/lane) + publish ----
        if (wave < BT) {
            const int d = lane;
            const float* grow = &ghT[wave][0];
            float rr = sigm(bias_r[d] + grow[d]);
            float zg = sigm(bias_z[d] + grow[64 + d]);
            float nn = tanh_(gin_[d] + rr * (bhn_[d] + grow[128 + d]));
            float h  = (1.f - zg) * nn + zg * hprev_reg;
            hprev_reg = h;
            hpack[wave][d] = f2bf(h);
            const u16 sq = (u16)(base + t);
            if (lane < NK) {   // same-wave LDS write->read: lgkmcnt-ordered
                u16 b0 = hpack[wave][3 * lane], b1 = hpack[wave][3 * lane + 1],
                    b2 = hpack[wave][3 * lane + 2];
                u64 rec = (u64)sq | ((u64)b0 << 16) | ((u64)b1 << 32) | ((u64)b2 << 48);
                ASTORE(&g_ring2[sc][g][s][wave][lane], rec);
            }
        }

        // ---- waves 8-11: projection out[:,tau,:] from sm16 (h(tau+1)=h(t-1)) ----
        const int tau = t - 2;
        const bool proj = (tau >= 0) && ((tau & 7) == s);
        if (proj && wave >= 8) {
            const int e  = (wave - 8) * 16 + nl;
            const int ec = (e < ENC) ? e : (ENC - 1);
            const u16* wrow = sOutW + ec * OWS + quad * 8;
            f4 accp = {0.f, 0.f, 0.f, 0.f};
#pragma unroll
            for (int kb = 0; kb < 16; ++kb) {
                bf8 av = *(const bf8*)(afrag_base + quad * 8 + kb * 32);
                bf8 wv = *(const bf8*)(wrow + kb * 32);
                accp = __builtin_amdgcn_mfma_f32_16x16x32_bf16(av, wv, accp, 0, 0, 0);
            }
            if (quad < 2 && e < ENC) {
                float ob = sOutB[e];
#pragma unroll
                for (int r = 0; r < 4; ++r) {
                    int m = quad * 4 + r;
                    out[(row0 + m) * (OUT_T * ENC) + tau * ENC + e] = accp[r] + ob;
                }
            }
        }
        if (proj) __syncthreads();  // C: protect sm16 before next stage overwrite
    }

    // ---- tail: tau=255 uses h(256) (slot 0, seq base+256); s==7 projects ----
    if (s == 7) {
        const u16 want = (u16)(base + WIN_);
        if (wave < BT)
            sm16[wave * AROW16 + d0 + lane] = f2bf(hprev_reg);
        if (wave >= 1 && wave < 8) {
            const int j = (s + wave) & 7;
            const u64* rb = &g_ring2[0][g][j][0][0];
            const int row = lane >> 3, k = lane & 7;
            {
                const u64* pp = rb + 7 * NKP + 21;
                long guard = 0;
                while ((u16)ALOAD(pp) != want && guard < (1L << 18)) ++guard;
            }
            const u64* p0 = rb + row * NKP + k;
            const bool v2 = (k + 16) < NK;
            u64 r0 = ALOAD(p0), r1 = ALOAD(p0 + 8), r2 = v2 ? ALOAD(p0 + 16) : 0;
            bool ok0 = ((u16)r0 == want), ok1 = ((u16)r1 == want),
                 ok2 = (!v2) || ((u16)r2 == want);
            long guard = 0;
            while (!__all(ok0 && ok1 && ok2) && guard < (1L << 18)) {
                if (!ok0) { r0 = ALOAD(p0);      ok0 = ((u16)r0 == want); }
                if (!ok1) { r1 = ALOAD(p0 + 8);  ok1 = ((u16)r1 == want); }
                if (!ok2) { r2 = ALOAD(p0 + 16); ok2 = ((u16)r2 == want); }
                ++guard;
            }
            u16* dst = sm16 + row * AROW16 + j * 64;
            int db = 3 * k;
            dst[db] = (u16)(r0 >> 16); dst[db + 1] = (u16)(r0 >> 32); dst[db + 2] = (u16)(r0 >> 48);
            db = 3 * (k + 8);
            dst[db] = (u16)(r1 >> 16); dst[db + 1] = (u16)(r1 >> 32); dst[db + 2] = (u16)(r1 >> 48);
            if (v2) {
                db = 3 * (k + 16);
                dst[db] = (u16)(r2 >> 16);
                if (db + 1 < DS) dst[db + 1] = (u16)(r2 >> 32);
                if (db + 2 < DS) dst[db + 2] = (u16)(r2 >> 48);
            }
        }
        __syncthreads();
        if (wave >= 8) {
            const int e  = (wave - 8) * 16 + nl;
            const int ec = (e < ENC) ? e : (ENC - 1);
            const u16* wrow = sOutW + ec * OWS + quad * 8;
            f4 accp = {0.f, 0.f, 0.f, 0.f};
#pragma unroll
            for (int kb = 0; kb < 16; ++kb) {
                bf8 av = *(const bf8*)(afrag_base + quad * 8 + kb * 32);
                bf8 wv = *(const bf8*)(wrow + kb * 32);
                accp = __builtin_amdgcn_mfma_f32_16x16x32_bf16(av, wv, accp, 0, 0, 0);
            }
            if (quad < 2 && e < ENC) {
                float ob = sOutB[e];
#pragma unroll
                for (int r = 0; r < 4; ++r) {
                    int m = quad * 4 + r;
                    out[(row0 + m) * (OUT_T * ENC) + 255 * ENC + e] = accp[r] + ob;
                }
            }
        }
    }

    // bump own launch counter (next launch's base)
    if (tid == 0) ASTORE(lc_own, sh_lc + 1ULL);
}

extern "C" void kernel_launch(void* const* d_in, const int* in_sizes, int n_in,
                              void* d_out, int out_size, void* d_ws, size_t ws_size,
                              hipStream_t stream) {
    const float* z    = (const float*)d_in[0];
    const float* hpw  = (const float*)d_in[1];
    const float* hpb  = (const float*)d_in[2];
    // d_in[3] = w_ih: unused by the reference (input gates are pure biases)
    const float* whh  = (const float*)d_in[4];
    const float* bih  = (const float*)d_in[5];
    const float* bhh  = (const float*)d_in[6];
    const float* outw = (const float*)d_in[7];
    const float* outb = (const float*)d_in[8];
    float* out = (float*)d_out;

    (void)d_ws; (void)ws_size;  // scratch lives in module .bss
    gru_fused<<<dim3(256), dim3(TPB), 0, stream>>>(
        z, hpw, hpb, whh, bih, bhh, outw, outb, out);
}